// Round 1
// baseline (531.663 us; speedup 1.0000x reference)
//
#include <hip/hip_runtime.h>

// NablaT 3D: out = sum over axes of backward-difference (divergence adjoint).
// x: [3, S, S, S] f32, out: [S, S, S] f32, S = 320.
// Per axis d (on channel d):  out[0] = -x[0]; out[i] = x[i-1]-x[i]; out[S-1] = x[S-2].
// Memory-bound: ideal traffic 393 MB read + 131 MB write -> ~87 us @ 6 TB/s.

constexpr int S = 320;
constexpr long long PLANE = (long long)S * S;       // 102400
constexpr long long VOL   = PLANE * S;              // 32,768,000
constexpr int SV = S / 4;                           // 80 float4 per row

__global__ __launch_bounds__(256) void nablat_kernel(
    const float* __restrict__ x, float* __restrict__ out)
{
    long long tid = (long long)blockIdx.x * 256 + threadIdx.x;
    if (tid >= VOL / 4) return;

    int kv      = (int)(tid % SV);
    long long t = tid / SV;
    int j       = (int)(t % S);
    int i       = (int)(t / S);
    int k0      = kv * 4;
    long long base = (long long)i * PLANE + (long long)j * S + k0;

    const float* __restrict__ x0 = x;               // channel 0: diff along i
    const float* __restrict__ x1 = x + VOL;         // channel 1: diff along j
    const float* __restrict__ x2 = x + 2 * VOL;     // channel 2: diff along k

    float a0, a1, a2, a3;

    // ---- axis 0 (i) on x0: plane-stride neighbors ----
    if (i == 0) {
        float4 c = *reinterpret_cast<const float4*>(x0 + base);
        a0 = -c.x; a1 = -c.y; a2 = -c.z; a3 = -c.w;
    } else if (i == S - 1) {
        float4 p = *reinterpret_cast<const float4*>(x0 + base - PLANE);
        a0 = p.x; a1 = p.y; a2 = p.z; a3 = p.w;
    } else {
        float4 p = *reinterpret_cast<const float4*>(x0 + base - PLANE);
        float4 c = *reinterpret_cast<const float4*>(x0 + base);
        a0 = p.x - c.x; a1 = p.y - c.y; a2 = p.z - c.z; a3 = p.w - c.w;
    }

    // ---- axis 1 (j) on x1: row-stride neighbors ----
    if (j == 0) {
        float4 c = *reinterpret_cast<const float4*>(x1 + base);
        a0 -= c.x; a1 -= c.y; a2 -= c.z; a3 -= c.w;
    } else if (j == S - 1) {
        float4 p = *reinterpret_cast<const float4*>(x1 + base - S);
        a0 += p.x; a1 += p.y; a2 += p.z; a3 += p.w;
    } else {
        float4 p = *reinterpret_cast<const float4*>(x1 + base - S);
        float4 c = *reinterpret_cast<const float4*>(x1 + base);
        a0 += p.x - c.x; a1 += p.y - c.y; a2 += p.z - c.z; a3 += p.w - c.w;
    }

    // ---- axis 2 (k) on x2: in-vector neighbors + one scalar overlap ----
    {
        float4 c = *reinterpret_cast<const float4*>(x2 + base);
        if (k0 == 0) {
            a0 += -c.x;                 // out[0] = -x[0]
        } else {
            float pm1 = x2[base - 1];
            a0 += pm1 - c.x;
        }
        a1 += c.x - c.y;
        a2 += c.y - c.z;
        if (k0 + 4 == S) {
            a3 += c.z;                  // out[S-1] = x[S-2]
        } else {
            a3 += c.z - c.w;
        }
    }

    float4 r; r.x = a0; r.y = a1; r.z = a2; r.w = a3;
    *reinterpret_cast<float4*>(out + base) = r;
}

extern "C" void kernel_launch(void* const* d_in, const int* in_sizes, int n_in,
                              void* d_out, int out_size, void* d_ws, size_t ws_size,
                              hipStream_t stream)
{
    const float* x = (const float*)d_in[0];
    float* out = (float*)d_out;
    const long long nvec = VOL / 4;                 // 8,192,000 float4 work items
    const int blocks = (int)((nvec + 255) / 256);   // 32000 blocks
    nablat_kernel<<<blocks, 256, 0, stream>>>(x, out);
}